// Round 1
// baseline (942.283 us; speedup 1.0000x reference)
//
#include <hip/hip_runtime.h>
#include <hip/hip_bf16.h>

// ---------------------------------------------------------------------------
// 4-layer GCN forward (PyG gcn_norm semantics: add self-loops, D^-1/2 A D^-1/2)
// Pipeline per call:
//   1. count in-degree per dst (edges only), dinv[i] = rsqrt(count+1)
//   2. exclusive scan -> CSR rowptr (row i has count[i]+1 entries)
//   3. scatter-fill CSR (self-loop + edges) with norm = dinv[src]*dinv[dst]
//   4. per layer: hW = h @ W (f32 tiled GEMM), then
//      h' = relu(SpMM(A_norm, hW) + b)   (no relu on last layer)
// ---------------------------------------------------------------------------

#define N_NODES_DEFAULT 100000
#define F_DIM 128

__global__ void count_dst_kernel(const int* __restrict__ dst, int* __restrict__ count, int E) {
    int e = blockIdx.x * blockDim.x + threadIdx.x;
    if (e < E) atomicAdd(&count[dst[e]], 1);
}

__global__ void dinv_kernel(const int* __restrict__ count, float* __restrict__ dinv, int n) {
    int i = blockIdx.x * blockDim.x + threadIdx.x;
    if (i < n) dinv[i] = rsqrtf((float)(count[i] + 1));  // +1 self-loop, always > 0
}

// single-block exclusive scan of (count[i]+1); writes rowptr[0..n] and writepos[0..n-1]
__global__ __launch_bounds__(1024) void scan_kernel(const int* __restrict__ count,
                                                    int* __restrict__ rowptr,
                                                    int* __restrict__ writepos, int n) {
    __shared__ int sums[1024];
    int t = threadIdx.x;
    int chunk = (n + 1023) >> 10;
    int start = t * chunk;
    int end = min(start + chunk, n);
    int s = 0;
    for (int i = start; i < end; ++i) s += count[i] + 1;
    sums[t] = s;
    __syncthreads();
    // Hillis-Steele inclusive scan
    for (int off = 1; off < 1024; off <<= 1) {
        int v = (t >= off) ? sums[t - off] : 0;
        __syncthreads();
        sums[t] += v;
        __syncthreads();
    }
    int offset = (t == 0) ? 0 : sums[t - 1];
    for (int i = start; i < end; ++i) {
        rowptr[i] = offset;
        writepos[i] = offset;
        offset += count[i] + 1;
    }
    if (t == 0) rowptr[n] = sums[1023];
}

__global__ void fill_self_kernel(int* __restrict__ writepos, int* __restrict__ col,
                                 float* __restrict__ val, const float* __restrict__ dinv, int n) {
    int i = blockIdx.x * blockDim.x + threadIdx.x;
    if (i < n) {
        int p = atomicAdd(&writepos[i], 1);
        col[p] = i;
        val[p] = dinv[i] * dinv[i];
    }
}

__global__ void fill_edges_kernel(const int* __restrict__ src, const int* __restrict__ dst,
                                  int* __restrict__ writepos, int* __restrict__ col,
                                  float* __restrict__ val, const float* __restrict__ dinv, int E) {
    int e = blockIdx.x * blockDim.x + threadIdx.x;
    if (e < E) {
        int s = src[e], d = dst[e];
        int p = atomicAdd(&writepos[d], 1);
        col[p] = s;
        val[p] = dinv[s] * dinv[d];
    }
}

// C[M][Nc] = A[M][K] @ B[K][Nc], f32, 64x64 tile, 4x4 microtile, K multiple of 16
__global__ __launch_bounds__(256) void gemm_kernel(const float* __restrict__ A,
                                                   const float* __restrict__ B,
                                                   float* __restrict__ C,
                                                   int M, int K, int Nc) {
    const int BM = 64, BN = 64, BK = 16, TM = 4, TN = 4;
    __shared__ float As[BK][BM + 1];
    __shared__ float Bs[BK][BN + 1];
    int tid = threadIdx.x;
    int tx = tid & 15, ty = tid >> 4;
    int rowBase = blockIdx.x * BM;
    int colBase = blockIdx.y * BN;
    float acc[TM][TN] = {};
    for (int kb = 0; kb < K; kb += BK) {
        for (int i = tid; i < BM * BK; i += 256) {
            int m = i >> 4, k = i & 15;
            int gr = rowBase + m;
            As[k][m] = (gr < M) ? A[(long)gr * K + kb + k] : 0.f;
        }
        for (int i = tid; i < BK * BN; i += 256) {
            int k = i >> 6, n = i & 63;
            int gc = colBase + n;
            Bs[k][n] = (gc < Nc) ? B[(long)(kb + k) * Nc + gc] : 0.f;
        }
        __syncthreads();
#pragma unroll
        for (int k = 0; k < BK; ++k) {
            float a[TM], b[TN];
#pragma unroll
            for (int i = 0; i < TM; ++i) a[i] = As[k][ty * TM + i];
#pragma unroll
            for (int j = 0; j < TN; ++j) b[j] = Bs[k][tx * TN + j];
#pragma unroll
            for (int i = 0; i < TM; ++i)
#pragma unroll
                for (int j = 0; j < TN; ++j) acc[i][j] += a[i] * b[j];
        }
        __syncthreads();
    }
#pragma unroll
    for (int i = 0; i < TM; ++i) {
        int r = rowBase + ty * TM + i;
        if (r >= M) continue;
#pragma unroll
        for (int j = 0; j < TN; ++j) {
            int c = colBase + tx * TN + j;
            if (c < Nc) C[(long)r * Nc + c] = acc[i][j];
        }
    }
}

// out[node][f] = relu( sum_j val[j] * H[col[j]][f] + bias[f] )
// one block (128 threads) per node; F <= 128
__global__ __launch_bounds__(128) void spmm_kernel(const int* __restrict__ rowptr,
                                                   const int* __restrict__ col,
                                                   const float* __restrict__ val,
                                                   const float* __restrict__ H,
                                                   const float* __restrict__ bias,
                                                   float* __restrict__ out,
                                                   int n, int F, int relu) {
    int node = blockIdx.x;
    int f = threadIdx.x;
    if (node >= n || f >= F) return;
    int s = rowptr[node], e = rowptr[node + 1];
    float acc = 0.f;
    for (int j = s; j < e; ++j) {
        int c = col[j];
        float v = val[j];
        acc += v * H[(long)c * F + f];
    }
    acc += bias[f];
    if (relu) acc = fmaxf(acc, 0.f);
    out[(long)node * F + f] = acc;
}

extern "C" void kernel_launch(void* const* d_in, const int* in_sizes, int n_in,
                              void* d_out, int out_size, void* d_ws, size_t ws_size,
                              hipStream_t stream) {
    const float* x = (const float*)d_in[0];
    const int* edge_index = (const int*)d_in[1];
    const float* W0 = (const float*)d_in[2];
    const float* b0 = (const float*)d_in[3];
    const float* W1 = (const float*)d_in[4];
    const float* b1 = (const float*)d_in[5];
    const float* W2 = (const float*)d_in[6];
    const float* b2 = (const float*)d_in[7];
    const float* W3 = (const float*)d_in[8];
    const float* b3 = (const float*)d_in[9];

    const int E = in_sizes[1] / 2;
    const int N = in_sizes[0] / F_DIM;
    const int C = in_sizes[9];  // b3 size = num_classes
    const int NNZ = E + N;

    const int* src = edge_index;
    const int* dst = edge_index + E;

    // workspace carve-up (aligned to 256B)
    char* ws = (char*)d_ws;
    size_t off = 0;
    auto carve = [&](size_t bytes) -> void* {
        void* p = ws + off;
        off = (off + bytes + 255) & ~(size_t)255;
        return p;
    };
    float* bufA = (float*)carve((size_t)N * F_DIM * sizeof(float));
    float* bufB = (float*)carve((size_t)N * F_DIM * sizeof(float));
    int* count = (int*)carve((size_t)N * sizeof(int));
    float* dinv = (float*)carve((size_t)N * sizeof(float));
    int* rowptr = (int*)carve((size_t)(N + 1) * sizeof(int));
    int* writepos = (int*)carve((size_t)N * sizeof(int));
    int* colbuf = (int*)carve((size_t)NNZ * sizeof(int));
    float* valbuf = (float*)carve((size_t)NNZ * sizeof(float));
    (void)ws_size;

    // 1. degree count
    hipMemsetAsync(count, 0, (size_t)N * sizeof(int), stream);
    {
        int blocks = (E + 255) / 256;
        count_dst_kernel<<<blocks, 256, 0, stream>>>(dst, count, E);
    }
    // 2. dinv
    {
        int blocks = (N + 255) / 256;
        dinv_kernel<<<blocks, 256, 0, stream>>>(count, dinv, N);
    }
    // 3. scan -> rowptr/writepos
    scan_kernel<<<1, 1024, 0, stream>>>(count, rowptr, writepos, N);
    // 4. fill CSR
    {
        int blocksN = (N + 255) / 256;
        int blocksE = (E + 255) / 256;
        fill_self_kernel<<<blocksN, 256, 0, stream>>>(writepos, colbuf, valbuf, dinv, N);
        fill_edges_kernel<<<blocksE, 256, 0, stream>>>(src, dst, writepos, colbuf, valbuf, dinv, E);
    }

    // layers
    dim3 gemm_block(256);
    dim3 gemm_grid_h((N + 63) / 64, (F_DIM + 63) / 64);  // 128 out feats
    dim3 gemm_grid_c((N + 63) / 64, (C + 63) / 64);      // 40 out feats

    // L0: x @ W0 -> bufA ; spmm+b0+relu -> bufB
    gemm_kernel<<<gemm_grid_h, gemm_block, 0, stream>>>(x, W0, bufA, N, F_DIM, F_DIM);
    spmm_kernel<<<N, 128, 0, stream>>>(rowptr, colbuf, valbuf, bufA, b0, bufB, N, F_DIM, 1);
    // L1
    gemm_kernel<<<gemm_grid_h, gemm_block, 0, stream>>>(bufB, W1, bufA, N, F_DIM, F_DIM);
    spmm_kernel<<<N, 128, 0, stream>>>(rowptr, colbuf, valbuf, bufA, b1, bufB, N, F_DIM, 1);
    // L2
    gemm_kernel<<<gemm_grid_h, gemm_block, 0, stream>>>(bufB, W2, bufA, N, F_DIM, F_DIM);
    spmm_kernel<<<N, 128, 0, stream>>>(rowptr, colbuf, valbuf, bufA, b2, bufB, N, F_DIM, 1);
    // L3: bufB @ W3 [128x40] -> bufA ; spmm+b3 (no relu) -> d_out
    gemm_kernel<<<gemm_grid_c, gemm_block, 0, stream>>>(bufB, W3, bufA, N, F_DIM, C);
    spmm_kernel<<<N, 128, 0, stream>>>(rowptr, colbuf, valbuf, bufA, b3, (float*)d_out, N, C, 0);
}

// Round 2
// 675.169 us; speedup vs baseline: 1.3956x; 1.3956x over previous
//
#include <hip/hip_runtime.h>
#include <hip/hip_bf16.h>

// ---------------------------------------------------------------------------
// 4-layer GCN forward (PyG gcn_norm: add self-loops, D^-1/2 A D^-1/2)
//   1. count in-degree per dst (edges only), dinv[i] = rsqrt(count+1)
//   2. two-level exclusive scan -> CSR rowptr (row i has count[i]+1 entries)
//   3. scatter-fill CSR (self-loop + edges) with norm = dinv[src]*dinv[dst]
//   4. per layer: hW = h @ W (f32 tiled GEMM), then
//      h' = relu(SpMM(A_norm, hW) + b)   (no relu on last layer)
// ---------------------------------------------------------------------------

#define F_DIM 128

#define SCAN_T 256
#define SCAN_I 8
#define SCAN_CHUNK (SCAN_T * SCAN_I)   // 2048 items per block

__global__ void count_dst_kernel(const int* __restrict__ dst, int* __restrict__ count, int E) {
    int e = blockIdx.x * blockDim.x + threadIdx.x;
    if (e < E) atomicAdd(&count[dst[e]], 1);
}

__global__ void dinv_kernel(const int* __restrict__ count, float* __restrict__ dinv, int n) {
    int i = blockIdx.x * blockDim.x + threadIdx.x;
    if (i < n) dinv[i] = rsqrtf((float)(count[i] + 1));  // +1 self-loop, always > 0
}

// ---- two-level scan of (count[i]+1) ---------------------------------------
__global__ __launch_bounds__(SCAN_T) void scan_partial_kernel(const int* __restrict__ count,
                                                              int* __restrict__ blocksum, int n) {
    int b = blockIdx.x, t = threadIdx.x;
    int base = b * SCAN_CHUNK + t * SCAN_I;
    int s = 0;
#pragma unroll
    for (int j = 0; j < SCAN_I; ++j) {
        int i = base + j;
        if (i < n) s += count[i] + 1;
    }
    __shared__ int red[SCAN_T];
    red[t] = s;
    __syncthreads();
    for (int off = SCAN_T / 2; off > 0; off >>= 1) {
        if (t < off) red[t] += red[t + off];
        __syncthreads();
    }
    if (t == 0) blocksum[b] = red[0];
}

// single block; nb <= 1024. exclusive scan; blockoff[nb] = total
__global__ __launch_bounds__(1024) void scan_sums_kernel(const int* __restrict__ blocksum,
                                                         int* __restrict__ blockoff, int nb) {
    __shared__ int sums[1024];
    int t = threadIdx.x;
    sums[t] = (t < nb) ? blocksum[t] : 0;
    __syncthreads();
    for (int off = 1; off < 1024; off <<= 1) {
        int v = (t >= off) ? sums[t - off] : 0;
        __syncthreads();
        sums[t] += v;
        __syncthreads();
    }
    if (t < nb) blockoff[t] = (t == 0) ? 0 : sums[t - 1];
    if (t == 0) blockoff[nb] = sums[nb - 1];
}

__global__ __launch_bounds__(SCAN_T) void scan_write_kernel(const int* __restrict__ count,
                                                            const int* __restrict__ blockoff,
                                                            int* __restrict__ rowptr,
                                                            int* __restrict__ writepos,
                                                            int n, int nb) {
    int b = blockIdx.x, t = threadIdx.x;
    int base = b * SCAN_CHUNK + t * SCAN_I;
    int c[SCAN_I];
    int s = 0;
#pragma unroll
    for (int j = 0; j < SCAN_I; ++j) {
        int i = base + j;
        c[j] = (i < n) ? count[i] + 1 : 0;
        s += c[j];
    }
    __shared__ int sums[SCAN_T];
    sums[t] = s;
    __syncthreads();
    for (int off = 1; off < SCAN_T; off <<= 1) {
        int v = (t >= off) ? sums[t - off] : 0;
        __syncthreads();
        sums[t] += v;
        __syncthreads();
    }
    int offset = blockoff[b] + ((t == 0) ? 0 : sums[t - 1]);
#pragma unroll
    for (int j = 0; j < SCAN_I; ++j) {
        int i = base + j;
        if (i < n) {
            rowptr[i] = offset;
            writepos[i] = offset;
            offset += c[j];
        }
    }
    if (b == 0 && t == 0) rowptr[n] = blockoff[nb];
}

// ---- CSR fill -------------------------------------------------------------
__global__ void fill_self_kernel(int* __restrict__ writepos, int* __restrict__ col,
                                 float* __restrict__ val, const float* __restrict__ dinv, int n) {
    int i = blockIdx.x * blockDim.x + threadIdx.x;
    if (i < n) {
        int p = atomicAdd(&writepos[i], 1);
        col[p] = i;
        val[p] = dinv[i] * dinv[i];
    }
}

__global__ void fill_edges_kernel(const int* __restrict__ src, const int* __restrict__ dst,
                                  int* __restrict__ writepos, int* __restrict__ col,
                                  float* __restrict__ val, const float* __restrict__ dinv, int E) {
    int e = blockIdx.x * blockDim.x + threadIdx.x;
    if (e < E) {
        int s = src[e], d = dst[e];
        int p = atomicAdd(&writepos[d], 1);
        col[p] = s;
        val[p] = dinv[s] * dinv[d];
    }
}

// ---- GEMM: C[M][Nc] = A[M][K] @ B[K][Nc], f32, 64x64 tile, 4x4 microtile --
// requires K % 16 == 0 (K = 128 here)
__global__ __launch_bounds__(256) void gemm_kernel(const float* __restrict__ A,
                                                   const float* __restrict__ B,
                                                   float* __restrict__ C,
                                                   int M, int K, int Nc) {
    const int BM = 64, BN = 64, BK = 16, TM = 4, TN = 4;
    __shared__ float As[BK][BM + 1];
    __shared__ float Bs[BK][BN + 1];
    int tid = threadIdx.x;
    int tx = tid & 15, ty = tid >> 4;
    int rowBase = blockIdx.x * BM;
    int colBase = blockIdx.y * BN;
    float acc[TM][TN] = {};

    // per-thread load coordinates (constant across K loop)
    int am = tid >> 2;            // 0..63
    int ak4 = (tid & 3) * 4;      // 0,4,8,12
    int bk = tid >> 4;            // 0..15
    int bn4 = (tid & 15) * 4;     // 0..60

    for (int kb = 0; kb < K; kb += BK) {
        // A tile: 64x16 via float4 (row-contiguous)
        {
            int gr = rowBase + am;
            float4 av = make_float4(0.f, 0.f, 0.f, 0.f);
            if (gr < M) av = *(const float4*)&A[(long)gr * K + kb + ak4];
            As[ak4 + 0][am] = av.x;
            As[ak4 + 1][am] = av.y;
            As[ak4 + 2][am] = av.z;
            As[ak4 + 3][am] = av.w;
        }
        // B tile: 16x64 via float4 when in-bounds
        {
            int gc = colBase + bn4;
            if (gc + 3 < Nc) {
                float4 bv = *(const float4*)&B[(long)(kb + bk) * Nc + gc];
                Bs[bk][bn4 + 0] = bv.x;
                Bs[bk][bn4 + 1] = bv.y;
                Bs[bk][bn4 + 2] = bv.z;
                Bs[bk][bn4 + 3] = bv.w;
            } else {
#pragma unroll
                for (int j = 0; j < 4; ++j)
                    Bs[bk][bn4 + j] = (gc + j < Nc) ? B[(long)(kb + bk) * Nc + gc + j] : 0.f;
            }
        }
        __syncthreads();
#pragma unroll
        for (int k = 0; k < BK; ++k) {
            float a[TM], b[TN];
#pragma unroll
            for (int i = 0; i < TM; ++i) a[i] = As[k][ty * TM + i];
#pragma unroll
            for (int j = 0; j < TN; ++j) b[j] = Bs[k][tx * TN + j];
#pragma unroll
            for (int i = 0; i < TM; ++i)
#pragma unroll
                for (int j = 0; j < TN; ++j) acc[i][j] += a[i] * b[j];
        }
        __syncthreads();
    }
#pragma unroll
    for (int i = 0; i < TM; ++i) {
        int r = rowBase + ty * TM + i;
        if (r >= M) continue;
#pragma unroll
        for (int j = 0; j < TN; ++j) {
            int c = colBase + tx * TN + j;
            if (c < Nc) C[(long)r * Nc + c] = acc[i][j];
        }
    }
}

// out[node][f] = relu( sum_j val[j] * H[col[j]][f] + bias[f] )
// one block (128 threads) per node; F <= 128
__global__ __launch_bounds__(128) void spmm_kernel(const int* __restrict__ rowptr,
                                                   const int* __restrict__ col,
                                                   const float* __restrict__ val,
                                                   const float* __restrict__ H,
                                                   const float* __restrict__ bias,
                                                   float* __restrict__ out,
                                                   int n, int F, int relu) {
    int node = blockIdx.x;
    int f = threadIdx.x;
    if (node >= n || f >= F) return;
    int s = rowptr[node], e = rowptr[node + 1];
    float acc = 0.f;
    for (int j = s; j < e; ++j) {
        int c = col[j];
        float v = val[j];
        acc += v * H[(long)c * F + f];
    }
    acc += bias[f];
    if (relu) acc = fmaxf(acc, 0.f);
    out[(long)node * F + f] = acc;
}

extern "C" void kernel_launch(void* const* d_in, const int* in_sizes, int n_in,
                              void* d_out, int out_size, void* d_ws, size_t ws_size,
                              hipStream_t stream) {
    const float* x = (const float*)d_in[0];
    const int* edge_index = (const int*)d_in[1];
    const float* W0 = (const float*)d_in[2];
    const float* b0 = (const float*)d_in[3];
    const float* W1 = (const float*)d_in[4];
    const float* b1 = (const float*)d_in[5];
    const float* W2 = (const float*)d_in[6];
    const float* b2 = (const float*)d_in[7];
    const float* W3 = (const float*)d_in[8];
    const float* b3 = (const float*)d_in[9];

    const int E = in_sizes[1] / 2;
    const int N = in_sizes[0] / F_DIM;
    const int C = in_sizes[9];  // b3 size = num_classes
    const int NNZ = E + N;
    const int NB = (N + SCAN_CHUNK - 1) / SCAN_CHUNK;

    const int* src = edge_index;
    const int* dst = edge_index + E;

    // workspace carve-up (aligned to 256B)
    char* ws = (char*)d_ws;
    size_t off = 0;
    auto carve = [&](size_t bytes) -> void* {
        void* p = ws + off;
        off = (off + bytes + 255) & ~(size_t)255;
        return p;
    };
    float* bufA = (float*)carve((size_t)N * F_DIM * sizeof(float));
    float* bufB = (float*)carve((size_t)N * F_DIM * sizeof(float));
    int* count = (int*)carve((size_t)N * sizeof(int));
    float* dinv = (float*)carve((size_t)N * sizeof(float));
    int* rowptr = (int*)carve((size_t)(N + 1) * sizeof(int));
    int* writepos = (int*)carve((size_t)N * sizeof(int));
    int* colbuf = (int*)carve((size_t)NNZ * sizeof(int));
    float* valbuf = (float*)carve((size_t)NNZ * sizeof(float));
    int* blocksum = (int*)carve((size_t)NB * sizeof(int));
    int* blockoff = (int*)carve((size_t)(NB + 1) * sizeof(int));
    (void)ws_size;

    // 1. degree count
    hipMemsetAsync(count, 0, (size_t)N * sizeof(int), stream);
    count_dst_kernel<<<(E + 255) / 256, 256, 0, stream>>>(dst, count, E);
    // 2. dinv
    dinv_kernel<<<(N + 255) / 256, 256, 0, stream>>>(count, dinv, N);
    // 3. two-level scan -> rowptr/writepos
    scan_partial_kernel<<<NB, SCAN_T, 0, stream>>>(count, blocksum, N);
    scan_sums_kernel<<<1, 1024, 0, stream>>>(blocksum, blockoff, NB);
    scan_write_kernel<<<NB, SCAN_T, 0, stream>>>(count, blockoff, rowptr, writepos, N, NB);
    // 4. fill CSR
    fill_self_kernel<<<(N + 255) / 256, 256, 0, stream>>>(writepos, colbuf, valbuf, dinv, N);
    fill_edges_kernel<<<(E + 255) / 256, 256, 0, stream>>>(src, dst, writepos, colbuf, valbuf, dinv, E);

    // layers
    dim3 gemm_block(256);
    dim3 gemm_grid_h((N + 63) / 64, (F_DIM + 63) / 64);  // 128 out feats
    dim3 gemm_grid_c((N + 63) / 64, (C + 63) / 64);      // 40 out feats

    // L0: x @ W0 -> bufA ; spmm+b0+relu -> bufB
    gemm_kernel<<<gemm_grid_h, gemm_block, 0, stream>>>(x, W0, bufA, N, F_DIM, F_DIM);
    spmm_kernel<<<N, 128, 0, stream>>>(rowptr, colbuf, valbuf, bufA, b0, bufB, N, F_DIM, 1);
    // L1
    gemm_kernel<<<gemm_grid_h, gemm_block, 0, stream>>>(bufB, W1, bufA, N, F_DIM, F_DIM);
    spmm_kernel<<<N, 128, 0, stream>>>(rowptr, colbuf, valbuf, bufA, b1, bufB, N, F_DIM, 1);
    // L2
    gemm_kernel<<<gemm_grid_h, gemm_block, 0, stream>>>(bufB, W2, bufA, N, F_DIM, F_DIM);
    spmm_kernel<<<N, 128, 0, stream>>>(rowptr, colbuf, valbuf, bufA, b2, bufB, N, F_DIM, 1);
    // L3: bufB @ W3 [128x40] -> bufA ; spmm+b3 (no relu) -> d_out
    gemm_kernel<<<gemm_grid_c, gemm_block, 0, stream>>>(bufB, W3, bufA, N, F_DIM, C);
    spmm_kernel<<<N, 128, 0, stream>>>(rowptr, colbuf, valbuf, bufA, b3, (float*)d_out, N, C, 0);
}

// Round 3
// 482.899 us; speedup vs baseline: 1.9513x; 1.3982x over previous
//
#include <hip/hip_runtime.h>
#include <hip/hip_bf16.h>

// ---------------------------------------------------------------------------
// 4-layer GCN forward (PyG gcn_norm: add self-loops, D^-1/2 A D^-1/2)
// Reassociated: h' = relu((A·h)·W + b)  [A·(hW) == (A·h)·W exactly]
// Hidden layers: ONE fused kernel per layer:
//   phase 1: gather/aggregate 64 node rows into LDS (float4 vectorized)
//   phase 2: 64x128 @ 128x128 GEMM from LDS, bias+relu epilogue
// Last layer: vectorized SpMM (agg) -> small GEMM 128->40 with bias.
// ---------------------------------------------------------------------------

#define F_DIM 128

#define SCAN_T 256
#define SCAN_I 8
#define SCAN_CHUNK (SCAN_T * SCAN_I)   // 2048 items per block

__global__ void count_dst_kernel(const int* __restrict__ dst, int* __restrict__ count, int E) {
    int e = blockIdx.x * blockDim.x + threadIdx.x;
    if (e < E) atomicAdd(&count[dst[e]], 1);
}

__global__ void dinv_kernel(const int* __restrict__ count, float* __restrict__ dinv, int n) {
    int i = blockIdx.x * blockDim.x + threadIdx.x;
    if (i < n) dinv[i] = rsqrtf((float)(count[i] + 1));  // +1 self-loop, always > 0
}

// ---- two-level scan of (count[i]+1) ---------------------------------------
__global__ __launch_bounds__(SCAN_T) void scan_partial_kernel(const int* __restrict__ count,
                                                              int* __restrict__ blocksum, int n) {
    int b = blockIdx.x, t = threadIdx.x;
    int base = b * SCAN_CHUNK + t * SCAN_I;
    int s = 0;
#pragma unroll
    for (int j = 0; j < SCAN_I; ++j) {
        int i = base + j;
        if (i < n) s += count[i] + 1;
    }
    __shared__ int red[SCAN_T];
    red[t] = s;
    __syncthreads();
    for (int off = SCAN_T / 2; off > 0; off >>= 1) {
        if (t < off) red[t] += red[t + off];
        __syncthreads();
    }
    if (t == 0) blocksum[b] = red[0];
}

__global__ __launch_bounds__(1024) void scan_sums_kernel(const int* __restrict__ blocksum,
                                                         int* __restrict__ blockoff, int nb) {
    __shared__ int sums[1024];
    int t = threadIdx.x;
    sums[t] = (t < nb) ? blocksum[t] : 0;
    __syncthreads();
    for (int off = 1; off < 1024; off <<= 1) {
        int v = (t >= off) ? sums[t - off] : 0;
        __syncthreads();
        sums[t] += v;
        __syncthreads();
    }
    if (t < nb) blockoff[t] = (t == 0) ? 0 : sums[t - 1];
    if (t == 0) blockoff[nb] = sums[nb - 1];
}

__global__ __launch_bounds__(SCAN_T) void scan_write_kernel(const int* __restrict__ count,
                                                            const int* __restrict__ blockoff,
                                                            int* __restrict__ rowptr,
                                                            int* __restrict__ writepos,
                                                            int n, int nb) {
    int b = blockIdx.x, t = threadIdx.x;
    int base = b * SCAN_CHUNK + t * SCAN_I;
    int c[SCAN_I];
    int s = 0;
#pragma unroll
    for (int j = 0; j < SCAN_I; ++j) {
        int i = base + j;
        c[j] = (i < n) ? count[i] + 1 : 0;
        s += c[j];
    }
    __shared__ int sums[SCAN_T];
    sums[t] = s;
    __syncthreads();
    for (int off = 1; off < SCAN_T; off <<= 1) {
        int v = (t >= off) ? sums[t - off] : 0;
        __syncthreads();
        sums[t] += v;
        __syncthreads();
    }
    int offset = blockoff[b] + ((t == 0) ? 0 : sums[t - 1]);
#pragma unroll
    for (int j = 0; j < SCAN_I; ++j) {
        int i = base + j;
        if (i < n) {
            rowptr[i] = offset;
            writepos[i] = offset;
            offset += c[j];
        }
    }
    if (b == 0 && t == 0) rowptr[n] = blockoff[nb];
}

// ---- CSR fill -------------------------------------------------------------
__global__ void fill_self_kernel(int* __restrict__ writepos, int* __restrict__ col,
                                 float* __restrict__ val, const float* __restrict__ dinv, int n) {
    int i = blockIdx.x * blockDim.x + threadIdx.x;
    if (i < n) {
        int p = atomicAdd(&writepos[i], 1);
        col[p] = i;
        val[p] = dinv[i] * dinv[i];
    }
}

__global__ void fill_edges_kernel(const int* __restrict__ src, const int* __restrict__ dst,
                                  int* __restrict__ writepos, int* __restrict__ col,
                                  float* __restrict__ val, const float* __restrict__ dinv, int E) {
    int e = blockIdx.x * blockDim.x + threadIdx.x;
    if (e < E) {
        int s = src[e], d = dst[e];
        int p = atomicAdd(&writepos[d], 1);
        col[p] = s;
        val[p] = dinv[s] * dinv[d];
    }
}

// ---- fused layer: out[64 nodes] = relu( (A·Hin)[64x128] @ W[128x128] + b ) -
// block = 256 threads, BM = 64 nodes/block
__global__ __launch_bounds__(256) void fused_layer_kernel(const int* __restrict__ rowptr,
                                                          const int* __restrict__ col,
                                                          const float* __restrict__ val,
                                                          const float* __restrict__ Hin,
                                                          const float* __restrict__ W,
                                                          const float* __restrict__ bias,
                                                          float* __restrict__ Hout,
                                                          int n) {
    // agg row stride 132: float4-aligned AND phase-2 a-reads (8 consecutive
    // rows per instr, bank step 132%32=4) conflict-free
    __shared__ float agg[64][132];
    __shared__ float Ws[16][128];

    const float4* H4 = (const float4*)Hin;
    const float4* W4 = (const float4*)W;

    // ---- phase 1: aggregate 64 rows into LDS ----
    {
        int m = threadIdx.x >> 2;        // node within tile 0..63
        int cq = threadIdx.x & 3;        // feature quarter (32 floats)
        int node = blockIdx.x * 64 + m;
        float4 acc[8];
#pragma unroll
        for (int q = 0; q < 8; ++q) acc[q] = make_float4(0.f, 0.f, 0.f, 0.f);
        if (node < n) {
            int s = rowptr[node], e = rowptr[node + 1];
            for (int j = s; j < e; ++j) {
                int c = col[j];
                float v = val[j];
                const float4* hp = H4 + (size_t)c * 32 + cq * 8;
#pragma unroll
                for (int q = 0; q < 8; ++q) {
                    float4 h = hp[q];
                    acc[q].x += v * h.x;
                    acc[q].y += v * h.y;
                    acc[q].z += v * h.z;
                    acc[q].w += v * h.w;
                }
            }
        }
#pragma unroll
        for (int q = 0; q < 8; ++q)
            *(float4*)&agg[m][cq * 32 + q * 4] = acc[q];
    }
    __syncthreads();

    // ---- phase 2: agg[64][128] @ W[128][128] ----
    int tx = threadIdx.x & 31;   // feat4 index: feats 4*tx..4*tx+3
    int ty = threadIdx.x >> 5;   // 0..7; thread's nodes are i*8+ty (i=0..7)
    float4 oacc[8];
#pragma unroll
    for (int i = 0; i < 8; ++i) oacc[i] = make_float4(0.f, 0.f, 0.f, 0.f);

    for (int kb = 0; kb < 128; kb += 16) {
        // stage W[kb..kb+16][0..128] (2048 floats, 2 float4/thread)
        {
            int r = threadIdx.x >> 5;
            int c4 = threadIdx.x & 31;
            *(float4*)&Ws[r][c4 * 4]     = W4[(size_t)(kb + r) * 32 + c4];
            *(float4*)&Ws[r + 8][c4 * 4] = W4[(size_t)(kb + r + 8) * 32 + c4];
        }
        __syncthreads();
#pragma unroll
        for (int k = 0; k < 16; ++k) {
            float4 b = *(const float4*)&Ws[k][tx * 4];
#pragma unroll
            for (int i = 0; i < 8; ++i) {
                float a = agg[i * 8 + ty][kb + k];
                oacc[i].x += a * b.x;
                oacc[i].y += a * b.y;
                oacc[i].z += a * b.z;
                oacc[i].w += a * b.w;
            }
        }
        __syncthreads();
    }

    // ---- epilogue: bias + relu ----
    float4 bv = *(const float4*)&bias[tx * 4];
#pragma unroll
    for (int i = 0; i < 8; ++i) {
        int node = blockIdx.x * 64 + i * 8 + ty;
        if (node < n) {
            float4 o;
            o.x = fmaxf(oacc[i].x + bv.x, 0.f);
            o.y = fmaxf(oacc[i].y + bv.y, 0.f);
            o.z = fmaxf(oacc[i].z + bv.z, 0.f);
            o.w = fmaxf(oacc[i].w + bv.w, 0.f);
            ((float4*)Hout)[(size_t)node * 32 + tx] = o;
        }
    }
}

// ---- vectorized SpMM (no bias/relu): out = A · H, F = 128 -----------------
__global__ __launch_bounds__(256) void spmm4_kernel(const int* __restrict__ rowptr,
                                                    const int* __restrict__ col,
                                                    const float* __restrict__ val,
                                                    const float* __restrict__ H,
                                                    float* __restrict__ out, int n) {
    int g = threadIdx.x >> 5;      // node sub 0..7
    int lane = threadIdx.x & 31;   // float4 index
    int node = blockIdx.x * 8 + g;
    if (node >= n) return;
    const float4* H4 = (const float4*)H;
    int s = rowptr[node], e = rowptr[node + 1];
    float4 acc = make_float4(0.f, 0.f, 0.f, 0.f);
    for (int j = s; j < e; ++j) {
        int c = col[j];
        float v = val[j];
        float4 h = H4[(size_t)c * 32 + lane];
        acc.x += v * h.x;
        acc.y += v * h.y;
        acc.z += v * h.z;
        acc.w += v * h.w;
    }
    ((float4*)out)[(size_t)node * 32 + lane] = acc;
}

// ---- GEMM: C = A @ B + bias (optional relu), 64x64 tile, K%16==0 ----------
__global__ __launch_bounds__(256) void gemm_kernel(const float* __restrict__ A,
                                                   const float* __restrict__ B,
                                                   float* __restrict__ C,
                                                   const float* __restrict__ bias,
                                                   int M, int K, int Nc, int relu) {
    const int BM = 64, BN = 64, BK = 16, TM = 4, TN = 4;
    __shared__ float As[BK][BM + 1];
    __shared__ float Bs[BK][BN + 1];
    int tid = threadIdx.x;
    int tx = tid & 15, ty = tid >> 4;
    int rowBase = blockIdx.x * BM;
    int colBase = blockIdx.y * BN;
    float acc[TM][TN] = {};

    int am = tid >> 2;
    int ak4 = (tid & 3) * 4;
    int bk = tid >> 4;
    int bn4 = (tid & 15) * 4;

    for (int kb = 0; kb < K; kb += BK) {
        {
            int gr = rowBase + am;
            float4 av = make_float4(0.f, 0.f, 0.f, 0.f);
            if (gr < M) av = *(const float4*)&A[(size_t)gr * K + kb + ak4];
            As[ak4 + 0][am] = av.x;
            As[ak4 + 1][am] = av.y;
            As[ak4 + 2][am] = av.z;
            As[ak4 + 3][am] = av.w;
        }
        {
            int gc = colBase + bn4;
            if (gc + 3 < Nc) {
                float4 bv = *(const float4*)&B[(size_t)(kb + bk) * Nc + gc];
                Bs[bk][bn4 + 0] = bv.x;
                Bs[bk][bn4 + 1] = bv.y;
                Bs[bk][bn4 + 2] = bv.z;
                Bs[bk][bn4 + 3] = bv.w;
            } else {
#pragma unroll
                for (int j = 0; j < 4; ++j)
                    Bs[bk][bn4 + j] = (gc + j < Nc) ? B[(size_t)(kb + bk) * Nc + gc + j] : 0.f;
            }
        }
        __syncthreads();
#pragma unroll
        for (int k = 0; k < BK; ++k) {
            float a[TM], b[TN];
#pragma unroll
            for (int i = 0; i < TM; ++i) a[i] = As[k][ty * TM + i];
#pragma unroll
            for (int j = 0; j < TN; ++j) b[j] = Bs[k][tx * TN + j];
#pragma unroll
            for (int i = 0; i < TM; ++i)
#pragma unroll
                for (int j = 0; j < TN; ++j) acc[i][j] += a[i] * b[j];
        }
        __syncthreads();
    }
#pragma unroll
    for (int i = 0; i < TM; ++i) {
        int r = rowBase + ty * TM + i;
        if (r >= M) continue;
#pragma unroll
        for (int j = 0; j < TN; ++j) {
            int c = colBase + tx * TN + j;
            if (c < Nc) {
                float o = acc[i][j] + (bias ? bias[c] : 0.f);
                if (relu) o = fmaxf(o, 0.f);
                C[(size_t)r * Nc + c] = o;
            }
        }
    }
}

extern "C" void kernel_launch(void* const* d_in, const int* in_sizes, int n_in,
                              void* d_out, int out_size, void* d_ws, size_t ws_size,
                              hipStream_t stream) {
    const float* x = (const float*)d_in[0];
    const int* edge_index = (const int*)d_in[1];
    const float* W0 = (const float*)d_in[2];
    const float* b0 = (const float*)d_in[3];
    const float* W1 = (const float*)d_in[4];
    const float* b1 = (const float*)d_in[5];
    const float* W2 = (const float*)d_in[6];
    const float* b2 = (const float*)d_in[7];
    const float* W3 = (const float*)d_in[8];
    const float* b3 = (const float*)d_in[9];

    const int E = in_sizes[1] / 2;
    const int N = in_sizes[0] / F_DIM;
    const int C = in_sizes[9];
    const int NNZ = E + N;
    const int NB = (N + SCAN_CHUNK - 1) / SCAN_CHUNK;

    const int* src = edge_index;
    const int* dst = edge_index + E;

    char* ws = (char*)d_ws;
    size_t off = 0;
    auto carve = [&](size_t bytes) -> void* {
        void* p = ws + off;
        off = (off + bytes + 255) & ~(size_t)255;
        return p;
    };
    float* bufA = (float*)carve((size_t)N * F_DIM * sizeof(float));
    float* bufB = (float*)carve((size_t)N * F_DIM * sizeof(float));
    int* count = (int*)carve((size_t)N * sizeof(int));
    float* dinv = (float*)carve((size_t)N * sizeof(float));
    int* rowptr = (int*)carve((size_t)(N + 1) * sizeof(int));
    int* writepos = (int*)carve((size_t)N * sizeof(int));
    int* colbuf = (int*)carve((size_t)NNZ * sizeof(int));
    float* valbuf = (float*)carve((size_t)NNZ * sizeof(float));
    int* blocksum = (int*)carve((size_t)NB * sizeof(int));
    int* blockoff = (int*)carve((size_t)(NB + 1) * sizeof(int));
    (void)ws_size;

    // preprocessing: degree -> dinv -> scan -> CSR fill
    hipMemsetAsync(count, 0, (size_t)N * sizeof(int), stream);
    count_dst_kernel<<<(E + 255) / 256, 256, 0, stream>>>(dst, count, E);
    dinv_kernel<<<(N + 255) / 256, 256, 0, stream>>>(count, dinv, N);
    scan_partial_kernel<<<NB, SCAN_T, 0, stream>>>(count, blocksum, N);
    scan_sums_kernel<<<1, 1024, 0, stream>>>(blocksum, blockoff, NB);
    scan_write_kernel<<<NB, SCAN_T, 0, stream>>>(count, blockoff, rowptr, writepos, N, NB);
    fill_self_kernel<<<(N + 255) / 256, 256, 0, stream>>>(writepos, colbuf, valbuf, dinv, N);
    fill_edges_kernel<<<(E + 255) / 256, 256, 0, stream>>>(src, dst, writepos, colbuf, valbuf, dinv, E);

    // hidden layers: h' = relu((A·h)·W + b), fully fused
    int nblk = (N + 63) / 64;
    fused_layer_kernel<<<nblk, 256, 0, stream>>>(rowptr, colbuf, valbuf, x, W0, b0, bufB, N);
    fused_layer_kernel<<<nblk, 256, 0, stream>>>(rowptr, colbuf, valbuf, bufB, W1, b1, bufA, N);
    fused_layer_kernel<<<nblk, 256, 0, stream>>>(rowptr, colbuf, valbuf, bufA, W2, b2, bufB, N);

    // last layer: agg = A·h3 (spmm4), then agg @ W3 + b3 -> d_out
    spmm4_kernel<<<(N + 7) / 8, 256, 0, stream>>>(rowptr, colbuf, valbuf, bufB, bufA, N);
    dim3 gemm_grid_c((N + 63) / 64, (C + 63) / 64);
    gemm_kernel<<<gemm_grid_c, 256, 0, stream>>>(bufA, W3, (float*)d_out, b3, N, F_DIM, C, 0);
}

// Round 4
// 440.552 us; speedup vs baseline: 2.1389x; 1.0961x over previous
//
#include <hip/hip_runtime.h>
#include <hip/hip_bf16.h>

// ---------------------------------------------------------------------------
// 4-layer GCN forward (PyG gcn_norm: add self-loops, D^-1/2 A D^-1/2)
// Reassociated: h' = relu((A·h)·W + b)  [A·(hW) == (A·h)·W exactly]
// ALL 4 layers fused: per block of 32 nodes:
//   phase 1: gather/aggregate 32 node rows into LDS (8 thr/node, float4)
//   phase 2: 32x128 @ 128xFOUT register GEMM, W read from L2, bias(+relu)
// ---------------------------------------------------------------------------

#define F_DIM 128

#define SCAN_T 256
#define SCAN_I 8
#define SCAN_CHUNK (SCAN_T * SCAN_I)   // 2048 items per block

__global__ void count_dst_kernel(const int* __restrict__ dst, int* __restrict__ count, int E) {
    int e = blockIdx.x * blockDim.x + threadIdx.x;
    if (e < E) atomicAdd(&count[dst[e]], 1);
}

__global__ void dinv_kernel(const int* __restrict__ count, float* __restrict__ dinv, int n) {
    int i = blockIdx.x * blockDim.x + threadIdx.x;
    if (i < n) dinv[i] = rsqrtf((float)(count[i] + 1));  // +1 self-loop, always > 0
}

// ---- two-level scan of (count[i]+1) ---------------------------------------
__global__ __launch_bounds__(SCAN_T) void scan_partial_kernel(const int* __restrict__ count,
                                                              int* __restrict__ blocksum, int n) {
    int b = blockIdx.x, t = threadIdx.x;
    int base = b * SCAN_CHUNK + t * SCAN_I;
    int s = 0;
#pragma unroll
    for (int j = 0; j < SCAN_I; ++j) {
        int i = base + j;
        if (i < n) s += count[i] + 1;
    }
    __shared__ int red[SCAN_T];
    red[t] = s;
    __syncthreads();
    for (int off = SCAN_T / 2; off > 0; off >>= 1) {
        if (t < off) red[t] += red[t + off];
        __syncthreads();
    }
    if (t == 0) blocksum[b] = red[0];
}

__global__ __launch_bounds__(1024) void scan_sums_kernel(const int* __restrict__ blocksum,
                                                         int* __restrict__ blockoff, int nb) {
    __shared__ int sums[1024];
    int t = threadIdx.x;
    sums[t] = (t < nb) ? blocksum[t] : 0;
    __syncthreads();
    for (int off = 1; off < 1024; off <<= 1) {
        int v = (t >= off) ? sums[t - off] : 0;
        __syncthreads();
        sums[t] += v;
        __syncthreads();
    }
    if (t < nb) blockoff[t] = (t == 0) ? 0 : sums[t - 1];
    if (t == 0) blockoff[nb] = sums[nb - 1];
}

__global__ __launch_bounds__(SCAN_T) void scan_write_kernel(const int* __restrict__ count,
                                                            const int* __restrict__ blockoff,
                                                            int* __restrict__ rowptr,
                                                            int* __restrict__ writepos,
                                                            int n, int nb) {
    int b = blockIdx.x, t = threadIdx.x;
    int base = b * SCAN_CHUNK + t * SCAN_I;
    int c[SCAN_I];
    int s = 0;
#pragma unroll
    for (int j = 0; j < SCAN_I; ++j) {
        int i = base + j;
        c[j] = (i < n) ? count[i] + 1 : 0;
        s += c[j];
    }
    __shared__ int sums[SCAN_T];
    sums[t] = s;
    __syncthreads();
    for (int off = 1; off < SCAN_T; off <<= 1) {
        int v = (t >= off) ? sums[t - off] : 0;
        __syncthreads();
        sums[t] += v;
        __syncthreads();
    }
    int offset = blockoff[b] + ((t == 0) ? 0 : sums[t - 1]);
#pragma unroll
    for (int j = 0; j < SCAN_I; ++j) {
        int i = base + j;
        if (i < n) {
            rowptr[i] = offset;
            writepos[i] = offset;
            offset += c[j];
        }
    }
    if (b == 0 && t == 0) rowptr[n] = blockoff[nb];
}

// ---- CSR fill -------------------------------------------------------------
__global__ void fill_self_kernel(int* __restrict__ writepos, int* __restrict__ col,
                                 float* __restrict__ val, const float* __restrict__ dinv, int n) {
    int i = blockIdx.x * blockDim.x + threadIdx.x;
    if (i < n) {
        int p = atomicAdd(&writepos[i], 1);
        col[p] = i;
        val[p] = dinv[i] * dinv[i];
    }
}

__global__ void fill_edges_kernel(const int* __restrict__ src, const int* __restrict__ dst,
                                  int* __restrict__ writepos, int* __restrict__ col,
                                  float* __restrict__ val, const float* __restrict__ dinv, int E) {
    int e = blockIdx.x * blockDim.x + threadIdx.x;
    if (e < E) {
        int s = src[e], d = dst[e];
        int p = atomicAdd(&writepos[d], 1);
        col[p] = s;
        val[p] = dinv[s] * dinv[d];
    }
}

// ---- fused layer: out[32 nodes] = act( (A·Hin)[32x128] @ W[128xFOUT] + b )
// FOUT4: output float4s per row (32 -> 128 feats, 10 -> 40 feats)
// block = 256 threads, BM = 32 nodes/block
template <int FOUT4, int RELU>
__global__ __launch_bounds__(256, 6) void fused_layer_kernel(const int* __restrict__ rowptr,
                                                             const int* __restrict__ col,
                                                             const float* __restrict__ val,
                                                             const float* __restrict__ Hin,
                                                             const float* __restrict__ W,
                                                             const float* __restrict__ bias,
                                                             float* __restrict__ Hout,
                                                             int n) {
    // row stride 132 floats: float4-aligned; phase-2 row-broadcast reads land
    // on distinct banks (4r mod 32); phase-1 b128 writes spread across quads.
    __shared__ float agg[32][132];

    const float4* H4 = (const float4*)Hin;
    const float4* W4 = (const float4*)W;

    // ---- phase 1: aggregate 32 rows into LDS, 8 threads per node ----
    {
        int m = threadIdx.x >> 3;        // node in tile 0..31
        int p = threadIdx.x & 7;         // 16-float slice
        int node = blockIdx.x * 32 + m;
        float4 acc[4];
#pragma unroll
        for (int q = 0; q < 4; ++q) acc[q] = make_float4(0.f, 0.f, 0.f, 0.f);
        if (node < n) {
            int s = rowptr[node], e = rowptr[node + 1];
            for (int j = s; j < e; ++j) {
                int c = col[j];
                float v = val[j];
                const float4* hp = H4 + (size_t)c * 32 + p * 4;
#pragma unroll
                for (int q = 0; q < 4; ++q) {
                    float4 h = hp[q];
                    acc[q].x += v * h.x;
                    acc[q].y += v * h.y;
                    acc[q].z += v * h.z;
                    acc[q].w += v * h.w;
                }
            }
        }
#pragma unroll
        for (int q = 0; q < 4; ++q)
            *(float4*)&agg[m][p * 16 + q * 4] = acc[q];
    }
    __syncthreads();

    // ---- phase 2: agg[32][128] @ W[128][FOUT] from L2, register GEMM ----
    constexpr int TXM = (FOUT4 > 16) ? 32 : 16;  // feat4 lanes
    constexpr int NG = 256 / TXM;                // row groups
    constexpr int ROWS = 32 / NG;                // rows per thread
    int tx = threadIdx.x & (TXM - 1);
    int ty = threadIdx.x / TXM;

    float4 oacc[ROWS];
#pragma unroll
    for (int i = 0; i < ROWS; ++i) oacc[i] = make_float4(0.f, 0.f, 0.f, 0.f);

    if (tx < FOUT4) {
#pragma unroll 4
        for (int k = 0; k < 128; ++k) {
            float4 b = W4[(size_t)k * FOUT4 + tx];
#pragma unroll
            for (int i = 0; i < ROWS; ++i) {
                float a = agg[i * NG + ty][k];
                oacc[i].x += a * b.x;
                oacc[i].y += a * b.y;
                oacc[i].z += a * b.z;
                oacc[i].w += a * b.w;
            }
        }

        float4 bv = ((const float4*)bias)[tx];
#pragma unroll
        for (int i = 0; i < ROWS; ++i) {
            int node = blockIdx.x * 32 + i * NG + ty;
            if (node < n) {
                float4 o;
                o.x = oacc[i].x + bv.x;
                o.y = oacc[i].y + bv.y;
                o.z = oacc[i].z + bv.z;
                o.w = oacc[i].w + bv.w;
                if (RELU) {
                    o.x = fmaxf(o.x, 0.f);
                    o.y = fmaxf(o.y, 0.f);
                    o.z = fmaxf(o.z, 0.f);
                    o.w = fmaxf(o.w, 0.f);
                }
                ((float4*)Hout)[(size_t)node * FOUT4 + tx] = o;
            }
        }
    }
}

extern "C" void kernel_launch(void* const* d_in, const int* in_sizes, int n_in,
                              void* d_out, int out_size, void* d_ws, size_t ws_size,
                              hipStream_t stream) {
    const float* x = (const float*)d_in[0];
    const int* edge_index = (const int*)d_in[1];
    const float* W0 = (const float*)d_in[2];
    const float* b0 = (const float*)d_in[3];
    const float* W1 = (const float*)d_in[4];
    const float* b1 = (const float*)d_in[5];
    const float* W2 = (const float*)d_in[6];
    const float* b2 = (const float*)d_in[7];
    const float* W3 = (const float*)d_in[8];
    const float* b3 = (const float*)d_in[9];

    const int E = in_sizes[1] / 2;
    const int N = in_sizes[0] / F_DIM;
    const int NNZ = E + N;
    const int NB = (N + SCAN_CHUNK - 1) / SCAN_CHUNK;

    const int* src = edge_index;
    const int* dst = edge_index + E;

    char* ws = (char*)d_ws;
    size_t off = 0;
    auto carve = [&](size_t bytes) -> void* {
        void* p = ws + off;
        off = (off + bytes + 255) & ~(size_t)255;
        return p;
    };
    float* bufA = (float*)carve((size_t)N * F_DIM * sizeof(float));
    float* bufB = (float*)carve((size_t)N * F_DIM * sizeof(float));
    int* count = (int*)carve((size_t)N * sizeof(int));
    float* dinv = (float*)carve((size_t)N * sizeof(float));
    int* rowptr = (int*)carve((size_t)(N + 1) * sizeof(int));
    int* writepos = (int*)carve((size_t)N * sizeof(int));
    int* colbuf = (int*)carve((size_t)NNZ * sizeof(int));
    float* valbuf = (float*)carve((size_t)NNZ * sizeof(float));
    int* blocksum = (int*)carve((size_t)NB * sizeof(int));
    int* blockoff = (int*)carve((size_t)(NB + 1) * sizeof(int));
    (void)ws_size;

    // preprocessing: degree -> dinv -> scan -> CSR fill
    hipMemsetAsync(count, 0, (size_t)N * sizeof(int), stream);
    count_dst_kernel<<<(E + 255) / 256, 256, 0, stream>>>(dst, count, E);
    dinv_kernel<<<(N + 255) / 256, 256, 0, stream>>>(count, dinv, N);
    scan_partial_kernel<<<NB, SCAN_T, 0, stream>>>(count, blocksum, N);
    scan_sums_kernel<<<1, 1024, 0, stream>>>(blocksum, blockoff, NB);
    scan_write_kernel<<<NB, SCAN_T, 0, stream>>>(count, blockoff, rowptr, writepos, N, NB);
    fill_self_kernel<<<(N + 255) / 256, 256, 0, stream>>>(writepos, colbuf, valbuf, dinv, N);
    fill_edges_kernel<<<(E + 255) / 256, 256, 0, stream>>>(src, dst, writepos, colbuf, valbuf, dinv, E);

    // 4 fused layers
    int nblk = (N + 31) / 32;
    fused_layer_kernel<32, 1><<<nblk, 256, 0, stream>>>(rowptr, colbuf, valbuf, x, W0, b0, bufB, N);
    fused_layer_kernel<32, 1><<<nblk, 256, 0, stream>>>(rowptr, colbuf, valbuf, bufB, W1, b1, bufA, N);
    fused_layer_kernel<32, 1><<<nblk, 256, 0, stream>>>(rowptr, colbuf, valbuf, bufA, W2, b2, bufB, N);
    fused_layer_kernel<10, 0><<<nblk, 256, 0, stream>>>(rowptr, colbuf, valbuf, bufB, W3, b3, (float*)d_out, N);
}

// Round 5
// 432.173 us; speedup vs baseline: 2.1803x; 1.0194x over previous
//
#include <hip/hip_runtime.h>
#include <hip/hip_bf16.h>

// ---------------------------------------------------------------------------
// 4-layer GCN forward (PyG gcn_norm: add self-loops, D^-1/2 A D^-1/2)
// Reassociated: h' = relu((A·h)·W + b)  [A·(hW) == (A·h)·W exactly]
// ALL 4 layers fused: per block of 32 nodes:
//   phase 1: gather/aggregate 32 node rows into LDS (8 thr/node, float4,
//            slice-INTERLEAVED so each wave instr reads contiguous 128B/row,
//            edge loop unrolled x2 for MLP)
//   phase 2: 32x128 @ 128xFOUT register GEMM, W read from L2, bias(+relu)
// ---------------------------------------------------------------------------

#define F_DIM 128

#define SCAN_T 256
#define SCAN_I 8
#define SCAN_CHUNK (SCAN_T * SCAN_I)   // 2048 items per block

__global__ void count_dst_kernel(const int* __restrict__ dst, int* __restrict__ count, int E) {
    int e = blockIdx.x * blockDim.x + threadIdx.x;
    if (e < E) atomicAdd(&count[dst[e]], 1);
}

__global__ void dinv_kernel(const int* __restrict__ count, float* __restrict__ dinv, int n) {
    int i = blockIdx.x * blockDim.x + threadIdx.x;
    if (i < n) dinv[i] = rsqrtf((float)(count[i] + 1));  // +1 self-loop, always > 0
}

// ---- two-level scan of (count[i]+1) ---------------------------------------
__global__ __launch_bounds__(SCAN_T) void scan_partial_kernel(const int* __restrict__ count,
                                                              int* __restrict__ blocksum, int n) {
    int b = blockIdx.x, t = threadIdx.x;
    int base = b * SCAN_CHUNK + t * SCAN_I;
    int s = 0;
#pragma unroll
    for (int j = 0; j < SCAN_I; ++j) {
        int i = base + j;
        if (i < n) s += count[i] + 1;
    }
    __shared__ int red[SCAN_T];
    red[t] = s;
    __syncthreads();
    for (int off = SCAN_T / 2; off > 0; off >>= 1) {
        if (t < off) red[t] += red[t + off];
        __syncthreads();
    }
    if (t == 0) blocksum[b] = red[0];
}

__global__ __launch_bounds__(1024) void scan_sums_kernel(const int* __restrict__ blocksum,
                                                         int* __restrict__ blockoff, int nb) {
    __shared__ int sums[1024];
    int t = threadIdx.x;
    sums[t] = (t < nb) ? blocksum[t] : 0;
    __syncthreads();
    for (int off = 1; off < 1024; off <<= 1) {
        int v = (t >= off) ? sums[t - off] : 0;
        __syncthreads();
        sums[t] += v;
        __syncthreads();
    }
    if (t < nb) blockoff[t] = (t == 0) ? 0 : sums[t - 1];
    if (t == 0) blockoff[nb] = sums[nb - 1];
}

__global__ __launch_bounds__(SCAN_T) void scan_write_kernel(const int* __restrict__ count,
                                                            const int* __restrict__ blockoff,
                                                            int* __restrict__ rowptr,
                                                            int* __restrict__ writepos,
                                                            int n, int nb) {
    int b = blockIdx.x, t = threadIdx.x;
    int base = b * SCAN_CHUNK + t * SCAN_I;
    int c[SCAN_I];
    int s = 0;
#pragma unroll
    for (int j = 0; j < SCAN_I; ++j) {
        int i = base + j;
        c[j] = (i < n) ? count[i] + 1 : 0;
        s += c[j];
    }
    __shared__ int sums[SCAN_T];
    sums[t] = s;
    __syncthreads();
    for (int off = 1; off < SCAN_T; off <<= 1) {
        int v = (t >= off) ? sums[t - off] : 0;
        __syncthreads();
        sums[t] += v;
        __syncthreads();
    }
    int offset = blockoff[b] + ((t == 0) ? 0 : sums[t - 1]);
#pragma unroll
    for (int j = 0; j < SCAN_I; ++j) {
        int i = base + j;
        if (i < n) {
            rowptr[i] = offset;
            writepos[i] = offset;
            offset += c[j];
        }
    }
    if (b == 0 && t == 0) rowptr[n] = blockoff[nb];
}

// ---- CSR fill -------------------------------------------------------------
__global__ void fill_self_kernel(int* __restrict__ writepos, int* __restrict__ col,
                                 float* __restrict__ val, const float* __restrict__ dinv, int n) {
    int i = blockIdx.x * blockDim.x + threadIdx.x;
    if (i < n) {
        int p = atomicAdd(&writepos[i], 1);
        col[p] = i;
        val[p] = dinv[i] * dinv[i];
    }
}

__global__ void fill_edges_kernel(const int* __restrict__ src, const int* __restrict__ dst,
                                  int* __restrict__ writepos, int* __restrict__ col,
                                  float* __restrict__ val, const float* __restrict__ dinv, int E) {
    int e = blockIdx.x * blockDim.x + threadIdx.x;
    if (e < E) {
        int s = src[e], d = dst[e];
        int p = atomicAdd(&writepos[d], 1);
        col[p] = s;
        val[p] = dinv[s] * dinv[d];
    }
}

// ---- fused layer: out[32 nodes] = act( (A·Hin)[32x128] @ W[128xFOUT] + b )
// FOUT4: output float4s per row (32 -> 128 feats, 10 -> 40 feats)
// block = 256 threads, BM = 32 nodes/block
template <int FOUT4, int RELU>
__global__ __launch_bounds__(256, 6) void fused_layer_kernel(const int* __restrict__ rowptr,
                                                             const int* __restrict__ col,
                                                             const float* __restrict__ val,
                                                             const float* __restrict__ Hin,
                                                             const float* __restrict__ W,
                                                             const float* __restrict__ bias,
                                                             float* __restrict__ Hout,
                                                             int n) {
    // row stride 132 floats: float4-aligned; phase-2 row-broadcast reads land
    // on distinct banks per ty (132 mod 32 = 4).
    __shared__ float agg[32][132];

    const float4* H4 = (const float4*)Hin;
    const float4* W4 = (const float4*)W;

    // ---- phase 1: aggregate 32 rows into LDS, 8 threads per node ----
    // Thread p of a node-group owns float4 indices {p, p+8, p+16, p+24}:
    // for a fixed q, the group's 8 lanes read 8 CONSECUTIVE float4s = one
    // fully-utilized 128B segment per row (vs 64B-strided before).
    {
        int m = threadIdx.x >> 3;        // node in tile 0..31
        int p = threadIdx.x & 7;         // lane in group
        int node = blockIdx.x * 32 + m;
        float4 acc[4];
#pragma unroll
        for (int q = 0; q < 4; ++q) acc[q] = make_float4(0.f, 0.f, 0.f, 0.f);
        if (node < n) {
            int s = rowptr[node], e = rowptr[node + 1];
            int j = s;
            // unroll x2: both edges' 8 float4 loads issued before accumulation
            for (; j + 1 < e; j += 2) {
                int c0 = col[j], c1 = col[j + 1];
                float v0 = val[j], v1 = val[j + 1];
                const float4* hp0 = H4 + (size_t)c0 * 32 + p;
                const float4* hp1 = H4 + (size_t)c1 * 32 + p;
                float4 h0[4], h1[4];
#pragma unroll
                for (int q = 0; q < 4; ++q) h0[q] = hp0[q * 8];
#pragma unroll
                for (int q = 0; q < 4; ++q) h1[q] = hp1[q * 8];
#pragma unroll
                for (int q = 0; q < 4; ++q) {
                    acc[q].x += v0 * h0[q].x + v1 * h1[q].x;
                    acc[q].y += v0 * h0[q].y + v1 * h1[q].y;
                    acc[q].z += v0 * h0[q].z + v1 * h1[q].z;
                    acc[q].w += v0 * h0[q].w + v1 * h1[q].w;
                }
            }
            if (j < e) {
                int c0 = col[j];
                float v0 = val[j];
                const float4* hp0 = H4 + (size_t)c0 * 32 + p;
#pragma unroll
                for (int q = 0; q < 4; ++q) {
                    float4 h = hp0[q * 8];
                    acc[q].x += v0 * h.x;
                    acc[q].y += v0 * h.y;
                    acc[q].z += v0 * h.z;
                    acc[q].w += v0 * h.w;
                }
            }
        }
#pragma unroll
        for (int q = 0; q < 4; ++q)
            *(float4*)&agg[m][(p + 8 * q) * 4] = acc[q];
    }
    __syncthreads();

    // ---- phase 2: agg[32][128] @ W[128][FOUT] from L2, register GEMM ----
    constexpr int TXM = (FOUT4 > 16) ? 32 : 16;  // feat4 lanes
    constexpr int NG = 256 / TXM;                // row groups
    constexpr int ROWS = 32 / NG;                // rows per thread
    int tx = threadIdx.x & (TXM - 1);
    int ty = threadIdx.x / TXM;

    float4 oacc[ROWS];
#pragma unroll
    for (int i = 0; i < ROWS; ++i) oacc[i] = make_float4(0.f, 0.f, 0.f, 0.f);

    if (tx < FOUT4) {
#pragma unroll 4
        for (int k = 0; k < 128; ++k) {
            float4 b = W4[(size_t)k * FOUT4 + tx];
#pragma unroll
            for (int i = 0; i < ROWS; ++i) {
                float a = agg[i * NG + ty][k];
                oacc[i].x += a * b.x;
                oacc[i].y += a * b.y;
                oacc[i].z += a * b.z;
                oacc[i].w += a * b.w;
            }
        }

        float4 bv = ((const float4*)bias)[tx];
#pragma unroll
        for (int i = 0; i < ROWS; ++i) {
            int node = blockIdx.x * 32 + i * NG + ty;
            if (node < n) {
                float4 o;
                o.x = oacc[i].x + bv.x;
                o.y = oacc[i].y + bv.y;
                o.z = oacc[i].z + bv.z;
                o.w = oacc[i].w + bv.w;
                if (RELU) {
                    o.x = fmaxf(o.x, 0.f);
                    o.y = fmaxf(o.y, 0.f);
                    o.z = fmaxf(o.z, 0.f);
                    o.w = fmaxf(o.w, 0.f);
                }
                ((float4*)Hout)[(size_t)node * FOUT4 + tx] = o;
            }
        }
    }
}

extern "C" void kernel_launch(void* const* d_in, const int* in_sizes, int n_in,
                              void* d_out, int out_size, void* d_ws, size_t ws_size,
                              hipStream_t stream) {
    const float* x = (const float*)d_in[0];
    const int* edge_index = (const int*)d_in[1];
    const float* W0 = (const float*)d_in[2];
    const float* b0 = (const float*)d_in[3];
    const float* W1 = (const float*)d_in[4];
    const float* b1 = (const float*)d_in[5];
    const float* W2 = (const float*)d_in[6];
    const float* b2 = (const float*)d_in[7];
    const float* W3 = (const float*)d_in[8];
    const float* b3 = (const float*)d_in[9];

    const int E = in_sizes[1] / 2;
    const int N = in_sizes[0] / F_DIM;
    const int NNZ = E + N;
    const int NB = (N + SCAN_CHUNK - 1) / SCAN_CHUNK;

    const int* src = edge_index;
    const int* dst = edge_index + E;

    char* ws = (char*)d_ws;
    size_t off = 0;
    auto carve = [&](size_t bytes) -> void* {
        void* p = ws + off;
        off = (off + bytes + 255) & ~(size_t)255;
        return p;
    };
    float* bufA = (float*)carve((size_t)N * F_DIM * sizeof(float));
    float* bufB = (float*)carve((size_t)N * F_DIM * sizeof(float));
    int* count = (int*)carve((size_t)N * sizeof(int));
    float* dinv = (float*)carve((size_t)N * sizeof(float));
    int* rowptr = (int*)carve((size_t)(N + 1) * sizeof(int));
    int* writepos = (int*)carve((size_t)N * sizeof(int));
    int* colbuf = (int*)carve((size_t)NNZ * sizeof(int));
    float* valbuf = (float*)carve((size_t)NNZ * sizeof(float));
    int* blocksum = (int*)carve((size_t)NB * sizeof(int));
    int* blockoff = (int*)carve((size_t)(NB + 1) * sizeof(int));
    (void)ws_size;

    // preprocessing: degree -> dinv -> scan -> CSR fill
    hipMemsetAsync(count, 0, (size_t)N * sizeof(int), stream);
    count_dst_kernel<<<(E + 255) / 256, 256, 0, stream>>>(dst, count, E);
    dinv_kernel<<<(N + 255) / 256, 256, 0, stream>>>(count, dinv, N);
    scan_partial_kernel<<<NB, SCAN_T, 0, stream>>>(count, blocksum, N);
    scan_sums_kernel<<<1, 1024, 0, stream>>>(blocksum, blockoff, NB);
    scan_write_kernel<<<NB, SCAN_T, 0, stream>>>(count, blockoff, rowptr, writepos, N, NB);
    fill_self_kernel<<<(N + 255) / 256, 256, 0, stream>>>(writepos, colbuf, valbuf, dinv, N);
    fill_edges_kernel<<<(E + 255) / 256, 256, 0, stream>>>(src, dst, writepos, colbuf, valbuf, dinv, E);

    // 4 fused layers
    int nblk = (N + 31) / 32;
    fused_layer_kernel<32, 1><<<nblk, 256, 0, stream>>>(rowptr, colbuf, valbuf, x, W0, b0, bufB, N);
    fused_layer_kernel<32, 1><<<nblk, 256, 0, stream>>>(rowptr, colbuf, valbuf, bufB, W1, b1, bufA, N);
    fused_layer_kernel<32, 1><<<nblk, 256, 0, stream>>>(rowptr, colbuf, valbuf, bufA, W2, b2, bufB, N);
    fused_layer_kernel<10, 0><<<nblk, 256, 0, stream>>>(rowptr, colbuf, valbuf, bufB, W3, b3, (float*)d_out, N);
}